// Round 1
// baseline (494.852 us; speedup 1.0000x reference)
//
#include <hip/hip_runtime.h>
#include <hip/hip_bf16.h>

#define T_TOK 512
#define H_DIM 1024
#define F_DIM 4096
#define NEXP  8

typedef __attribute__((ext_vector_type(8))) short bf16x8;
typedef __attribute__((ext_vector_type(4))) float f32x4;

__device__ __forceinline__ short f2bs(float f) {
    __hip_bfloat16 h = __float2bfloat16(f);
    return __builtin_bit_cast(short, h);
}

// ---------------- routing: logits (fp32 exact) + phi_routing + x->bf16 ----------------
__global__ __launch_bounds__(256) void routing_kernel(
    const float* __restrict__ x, const float* __restrict__ gw,
    int* __restrict__ cnt, int* __restrict__ tok, float* __restrict__ wgt,
    __hip_bfloat16* __restrict__ xbf)
{
    int wave = threadIdx.x >> 6, lane = threadIdx.x & 63;
    int t = blockIdx.x * 4 + wave;
    const float* xr = x + (size_t)t * H_DIM;

    float xv[16];
    #pragma unroll
    for (int j = 0; j < 16; ++j) xv[j] = xr[lane + 64 * j];
    #pragma unroll
    for (int j = 0; j < 16; ++j)
        xbf[(size_t)t * H_DIM + lane + 64 * j] = __float2bfloat16(xv[j]);

    float lg[8];
    #pragma unroll
    for (int e = 0; e < 8; ++e) {
        const float* g = gw + (size_t)e * H_DIM;
        float s = 0.f;
        #pragma unroll
        for (int j = 0; j < 16; ++j) s += xv[j] * g[lane + 64 * j];
        #pragma unroll
        for (int d = 1; d < 64; d <<= 1) s += __shfl_xor(s, d);
        lg[e] = s;
    }

    // top-2 (ties -> lowest index, matches lax.top_k)
    float m1 = -1e30f; int i1 = 0;
    #pragma unroll
    for (int e = 0; e < 8; ++e) if (lg[e] > m1) { m1 = lg[e]; i1 = e; }
    float m2 = -1e30f; int i2 = 0;
    #pragma unroll
    for (int e = 0; e < 8; ++e) if (e != i1 && lg[e] > m2) { m2 = lg[e]; i2 = e; }

    // mirror jax: masked iff (m - l)/factor > 0.02 (NaN -> not masked)
    float s1 = 0.f, s2 = 0.f;
    #pragma unroll
    for (int e = 0; e < 8; ++e) {
        float fac1 = fmaxf(fabsf(lg[e]), m1);
        if (!((m1 - lg[e]) / fac1 > 0.02f)) s1 += expf(lg[e] - m1);
        if (e != i1) {
            float fac2 = fmaxf(fabsf(lg[e]), m2);
            if (!((m2 - lg[e]) / fac2 > 0.02f)) s2 += expf(lg[e] - m2);
        }
    }
    if (lane == 0) {
        float mult1 = 1.f / s1, mult2 = 1.f / s2;
        int p1 = atomicAdd(&cnt[i1], 1);
        tok[i1 * T_TOK + p1] = t; wgt[i1 * T_TOK + p1] = mult1;
        int p2 = atomicAdd(&cnt[i2], 1);
        tok[i2 * T_TOK + p2] = t; wgt[i2 * T_TOK + p2] = mult2;
    }
}

// ---------------- ffn1: h = silu(x@w1^T) * (x@w3^T), bf16 MFMA, no LDS ----------------
__global__ __launch_bounds__(256) void ffn1_kernel(
    const float* __restrict__ w1, const float* __restrict__ w3,
    const __hip_bfloat16* __restrict__ xbf,
    __hip_bfloat16* __restrict__ hbuf,
    const int* __restrict__ cnt, const int* __restrict__ tok)
{
    int e = blockIdx.y;
    int c[8];
    #pragma unroll
    for (int j = 0; j < 8; ++j) c[j] = cnt[j];
    int nt = c[e];
    int offE = 0;
    #pragma unroll
    for (int j = 0; j < 8; ++j) if (j < e) offE += c[j];

    int m0 = blockIdx.z * 256;
    if (m0 >= nt) return;
    int nact = min(nt - m0, 256);
    int f0 = blockIdx.x * 32;

    int wv = threadIdx.x >> 6, lane = threadIdx.x & 63;
    int lr = lane & 15, kg = lane >> 4;

    int rem = nact - wv * 64;
    int actn = (rem <= 0) ? 0 : min((rem + 15) >> 4, 4);
    if (actn == 0) return;

    const __hip_bfloat16* ap[4];
    #pragma unroll
    for (int mi = 0; mi < 4; ++mi) {
        int row = m0 + wv * 64 + mi * 16 + lr;
        int rc = min(row, nt - 1);
        int tt = tok[e * T_TOK + rc];
        ap[mi] = xbf + (size_t)tt * H_DIM + kg * 8;
    }
    const float* bp[4];
    const float* w1e = w1 + (size_t)e * F_DIM * H_DIM;
    const float* w3e = w3 + (size_t)e * F_DIM * H_DIM;
    #pragma unroll
    for (int ni = 0; ni < 2; ++ni) {
        bp[ni]     = w1e + (size_t)(f0 + ni * 16 + lr) * H_DIM + kg * 8;
        bp[ni + 2] = w3e + (size_t)(f0 + ni * 16 + lr) * H_DIM + kg * 8;
    }

    f32x4 acc[4][4];
    #pragma unroll
    for (int mi = 0; mi < 4; ++mi)
        #pragma unroll
        for (int ni = 0; ni < 4; ++ni) acc[mi][ni] = (f32x4){0.f, 0.f, 0.f, 0.f};

    auto load_ab = [&](bf16x8* a, bf16x8* b, int kk) {
        #pragma unroll
        for (int mi = 0; mi < 4; ++mi)
            a[mi] = *reinterpret_cast<const bf16x8*>(ap[mi] + kk);
        #pragma unroll
        for (int ni = 0; ni < 4; ++ni) {
            f32x4 lo = *reinterpret_cast<const f32x4*>(bp[ni] + kk);
            f32x4 hi = *reinterpret_cast<const f32x4*>(bp[ni] + kk + 4);
            bf16x8 tb;
            #pragma unroll
            for (int j = 0; j < 4; ++j) { tb[j] = f2bs(lo[j]); tb[4 + j] = f2bs(hi[j]); }
            b[ni] = tb;
        }
    };
    auto do_mfma = [&](bf16x8* a, bf16x8* b) {
        #pragma unroll
        for (int mi = 0; mi < 4; ++mi) {
            if (mi >= actn) break;
            #pragma unroll
            for (int ni = 0; ni < 4; ++ni)
                acc[mi][ni] = __builtin_amdgcn_mfma_f32_16x16x32_bf16(a[mi], b[ni], acc[mi][ni], 0, 0, 0);
        }
    };

    bf16x8 a0[4], b0[4], a1[4], b1[4];
    load_ab(a0, b0, 0);
    for (int k = 0; k < H_DIM; k += 64) {
        load_ab(a1, b1, k + 32);
        do_mfma(a0, b0);
        if (k + 64 < H_DIM) load_ab(a0, b0, k + 64);
        do_mfma(a1, b1);
    }

    // epilogue: pair w1-frag (ni) with w3-frag (ni+2), silu multiply, store bf16
    #pragma unroll
    for (int mi = 0; mi < 4; ++mi) {
        if (mi >= actn) break;
        #pragma unroll
        for (int ni = 0; ni < 2; ++ni) {
            f32x4 d1 = acc[mi][ni], d3 = acc[mi][ni + 2];
            int fc = f0 + ni * 16 + lr;
            #pragma unroll
            for (int r = 0; r < 4; ++r) {
                int rl = wv * 64 + mi * 16 + kg * 4 + r;
                if (rl < nact) {
                    float v1 = d1[r];
                    float hv = (v1 / (1.f + expf(-v1))) * d3[r];
                    hbuf[(size_t)(offE + m0 + rl) * F_DIM + fc] = __float2bfloat16(hv);
                }
            }
        }
    }
}

// ---------------- ffn2: out += wgt * (h @ w2^T), atomic fp32 accumulate ----------------
__global__ __launch_bounds__(256) void ffn2_kernel(
    const float* __restrict__ w2,
    const __hip_bfloat16* __restrict__ hbuf,
    const int* __restrict__ cnt, const int* __restrict__ tok,
    const float* __restrict__ wgt,
    float* __restrict__ out)
{
    int e = blockIdx.y;
    int c[8];
    #pragma unroll
    for (int j = 0; j < 8; ++j) c[j] = cnt[j];
    int nt = c[e];
    int offE = 0;
    #pragma unroll
    for (int j = 0; j < 8; ++j) if (j < e) offE += c[j];

    int mt = blockIdx.z >> 1, ks = blockIdx.z & 1;
    int m0 = mt * 256;
    if (m0 >= nt) return;
    int nact = min(nt - m0, 256);
    int n0 = blockIdx.x * 64;

    int wv = threadIdx.x >> 6, lane = threadIdx.x & 63;
    int lr = lane & 15, kg = lane >> 4;

    int rem = nact - wv * 64;
    int actn = (rem <= 0) ? 0 : min((rem + 15) >> 4, 4);
    if (actn == 0) return;

    const __hip_bfloat16* ap[4];
    #pragma unroll
    for (int mi = 0; mi < 4; ++mi) {
        int rl = wv * 64 + mi * 16 + lr;
        int rc = min(rl, nact - 1);
        ap[mi] = hbuf + (size_t)(offE + m0 + rc) * F_DIM + kg * 8;
    }
    const float* bp[4];
    const float* w2e = w2 + (size_t)e * H_DIM * F_DIM;
    #pragma unroll
    for (int ni = 0; ni < 4; ++ni)
        bp[ni] = w2e + (size_t)(n0 + ni * 16 + lr) * F_DIM + kg * 8;

    f32x4 acc[4][4];
    #pragma unroll
    for (int mi = 0; mi < 4; ++mi)
        #pragma unroll
        for (int ni = 0; ni < 4; ++ni) acc[mi][ni] = (f32x4){0.f, 0.f, 0.f, 0.f};

    auto load_ab = [&](bf16x8* a, bf16x8* b, int kk) {
        #pragma unroll
        for (int mi = 0; mi < 4; ++mi)
            a[mi] = *reinterpret_cast<const bf16x8*>(ap[mi] + kk);
        #pragma unroll
        for (int ni = 0; ni < 4; ++ni) {
            f32x4 lo = *reinterpret_cast<const f32x4*>(bp[ni] + kk);
            f32x4 hi = *reinterpret_cast<const f32x4*>(bp[ni] + kk + 4);
            bf16x8 tb;
            #pragma unroll
            for (int j = 0; j < 4; ++j) { tb[j] = f2bs(lo[j]); tb[4 + j] = f2bs(hi[j]); }
            b[ni] = tb;
        }
    };
    auto do_mfma = [&](bf16x8* a, bf16x8* b) {
        #pragma unroll
        for (int mi = 0; mi < 4; ++mi) {
            if (mi >= actn) break;
            #pragma unroll
            for (int ni = 0; ni < 4; ++ni)
                acc[mi][ni] = __builtin_amdgcn_mfma_f32_16x16x32_bf16(a[mi], b[ni], acc[mi][ni], 0, 0, 0);
        }
    };

    int kbeg = ks * 2048, kend = kbeg + 2048;
    bf16x8 a0[4], b0[4], a1[4], b1[4];
    load_ab(a0, b0, kbeg);
    for (int k = kbeg; k < kend; k += 64) {
        load_ab(a1, b1, k + 32);
        do_mfma(a0, b0);
        if (k + 64 < kend) load_ab(a0, b0, k + 64);
        do_mfma(a1, b1);
    }

    #pragma unroll
    for (int mi = 0; mi < 4; ++mi) {
        if (mi >= actn) break;
        #pragma unroll
        for (int ni = 0; ni < 4; ++ni) {
            f32x4 d = acc[mi][ni];
            int col = n0 + ni * 16 + lr;
            #pragma unroll
            for (int r = 0; r < 4; ++r) {
                int rl = wv * 64 + mi * 16 + kg * 4 + r;
                if (rl < nact) {
                    int sl = m0 + rl;
                    int tt = tok[e * T_TOK + sl];
                    float wvv = wgt[e * T_TOK + sl];
                    atomicAdd(&out[(size_t)tt * H_DIM + col], wvv * d[r]);
                }
            }
        }
    }
}

extern "C" void kernel_launch(void* const* d_in, const int* in_sizes, int n_in,
                              void* d_out, int out_size, void* d_ws, size_t ws_size,
                              hipStream_t stream)
{
    const float* x  = (const float*)d_in[0];
    const float* gw = (const float*)d_in[1];
    const float* w1 = (const float*)d_in[2];
    const float* w2 = (const float*)d_in[3];
    const float* w3 = (const float*)d_in[4];
    float* out = (float*)d_out;

    char* ws = (char*)d_ws;
    int*   cnt = (int*)(ws);
    int*   tok = (int*)(ws + 256);
    float* wgt = (float*)(ws + 16640);
    __hip_bfloat16* xbf  = (__hip_bfloat16*)(ws + 33280);
    __hip_bfloat16* hbuf = (__hip_bfloat16*)(ws + 1081856);

    hipMemsetAsync(cnt, 0, 256, stream);
    hipMemsetAsync(out, 0, (size_t)out_size * sizeof(float), stream);

    routing_kernel<<<dim3(T_TOK / 4), 256, 0, stream>>>(x, gw, cnt, tok, wgt, xbf);
    ffn1_kernel<<<dim3(F_DIM / 32, NEXP, 2), 256, 0, stream>>>(w1, w3, xbf, hbuf, cnt, tok);
    ffn2_kernel<<<dim3(H_DIM / 64, NEXP, 4), 256, 0, stream>>>(w2, hbuf, cnt, tok, wgt, out);
}

// Round 2
// 449.569 us; speedup vs baseline: 1.1007x; 1.1007x over previous
//
#include <hip/hip_runtime.h>
#include <hip/hip_bf16.h>

#define T_TOK 512
#define H_DIM 1024
#define F_DIM 4096
#define NEXP  8

typedef __attribute__((ext_vector_type(8))) short bf16x8;
typedef __attribute__((ext_vector_type(4))) float f32x4;

__device__ __forceinline__ short f2bs(float f) {
    __hip_bfloat16 h = __float2bfloat16(f);
    return __builtin_bit_cast(short, h);
}

// async global->LDS, 16B per lane (literal size arg required)
#define GLOAD_LDS16(SRC, DST)                                                              \
    __builtin_amdgcn_global_load_lds(                                                      \
        (const __attribute__((address_space(1))) unsigned int*)(SRC),                      \
        (__attribute__((address_space(3))) unsigned int*)(DST), 16, 0, 0)

// ---------------- routing: logits (fp32 exact) + phi_routing + x->bf16 ----------------
__global__ __launch_bounds__(256) void routing_kernel(
    const float* __restrict__ x, const float* __restrict__ gw,
    int* __restrict__ cnt, int* __restrict__ tok, float* __restrict__ wgt,
    __hip_bfloat16* __restrict__ xbf)
{
    int wave = threadIdx.x >> 6, lane = threadIdx.x & 63;
    int t = blockIdx.x * 4 + wave;
    const float* xr = x + (size_t)t * H_DIM;

    float xv[16];
    #pragma unroll
    for (int j = 0; j < 16; ++j) xv[j] = xr[lane + 64 * j];
    #pragma unroll
    for (int j = 0; j < 16; ++j)
        xbf[(size_t)t * H_DIM + lane + 64 * j] = __float2bfloat16(xv[j]);

    float lg[8];
    #pragma unroll
    for (int e = 0; e < 8; ++e) {
        const float* g = gw + (size_t)e * H_DIM;
        float s = 0.f;
        #pragma unroll
        for (int j = 0; j < 16; ++j) s += xv[j] * g[lane + 64 * j];
        #pragma unroll
        for (int d = 1; d < 64; d <<= 1) s += __shfl_xor(s, d);
        lg[e] = s;
    }

    float m1 = -1e30f; int i1 = 0;
    #pragma unroll
    for (int e = 0; e < 8; ++e) if (lg[e] > m1) { m1 = lg[e]; i1 = e; }
    float m2 = -1e30f; int i2 = 0;
    #pragma unroll
    for (int e = 0; e < 8; ++e) if (e != i1 && lg[e] > m2) { m2 = lg[e]; i2 = e; }

    float s1 = 0.f, s2 = 0.f;
    #pragma unroll
    for (int e = 0; e < 8; ++e) {
        float fac1 = fmaxf(fabsf(lg[e]), m1);
        if (!((m1 - lg[e]) / fac1 > 0.02f)) s1 += expf(lg[e] - m1);
        if (e != i1) {
            float fac2 = fmaxf(fabsf(lg[e]), m2);
            if (!((m2 - lg[e]) / fac2 > 0.02f)) s2 += expf(lg[e] - m2);
        }
    }
    if (lane == 0) {
        float mult1 = 1.f / s1, mult2 = 1.f / s2;
        int p1 = atomicAdd(&cnt[i1], 1);
        tok[i1 * T_TOK + p1] = t; wgt[i1 * T_TOK + p1] = mult1;
        int p2 = atomicAdd(&cnt[i2], 1);
        tok[i2 * T_TOK + p2] = t; wgt[i2 * T_TOK + p2] = mult2;
    }
}

// ---------------- ffn1: h = silu(x@w1^T) * (x@w3^T) ----------------
// B tile (64 rows = 32 w1-rows + 32 w3-rows) x (64 k) fp32, staged to LDS via
// global_load_lds with source-side XOR swizzle byte^((row&7)<<5) (read applies same XOR).
__global__ __launch_bounds__(256, 3) void ffn1_kernel(
    const float* __restrict__ w1, const float* __restrict__ w3,
    const __hip_bfloat16* __restrict__ xbf,
    __hip_bfloat16* __restrict__ hbuf,
    const int* __restrict__ cnt, const int* __restrict__ tok)
{
    __shared__ char sm[32768];  // 2 x 16KB double buffer

    int e = blockIdx.y;
    int c[8];
    #pragma unroll
    for (int j = 0; j < 8; ++j) c[j] = cnt[j];
    int nt = c[e];
    int offE = 0;
    #pragma unroll
    for (int j = 0; j < 8; ++j) if (j < e) offE += c[j];

    int m0 = blockIdx.z * 256;
    if (m0 >= nt) return;
    int nact = min(nt - m0, 256);
    int f0 = blockIdx.x * 32;

    int tid = threadIdx.x;
    int wv = tid >> 6, lane = tid & 63;
    int lr = lane & 15, kg = lane >> 4;
    int rem = nact - wv * 64;
    int actn = (rem <= 0) ? 0 : min((rem + 15) >> 4, 4);

    const float* w1e = w1 + (size_t)e * F_DIM * H_DIM;
    const float* w3e = w3 + (size_t)e * F_DIM * H_DIM;

    // A fragment pointers (bf16 activations, L2-resident)
    const __hip_bfloat16* ap[4];
    #pragma unroll
    for (int mi = 0; mi < 4; ++mi) {
        int row = m0 + wv * 64 + mi * 16 + lr;
        int rc = min(row, nt - 1);
        int tt = tok[e * T_TOK + rc];
        ap[mi] = xbf + (size_t)tt * H_DIM + kg * 8;
    }

    // staging: 4 instrs/thread, each lane 16B. LDS linear L = i*4096 + tid*16.
    // tile row r = L>>8 = i*16 + tid/16 ; within-row byte = (tid&15)*16, src pre-swizzled.
    const float* sb[4];
    int dstL[4];
    #pragma unroll
    for (int i = 0; i < 4; ++i) {
        int r = i * 16 + (tid >> 4);
        int cb = ((tid & 15) << 4) ^ ((r & 7) << 5);
        const float* base = (r < 32) ? w1e + (size_t)(f0 + r) * H_DIM
                                     : w3e + (size_t)(f0 + r - 32) * H_DIM;
        sb[i] = base + (cb >> 2);
        dstL[i] = i * 4096 + tid * 16;
    }

    auto STAGE = [&](int buf, int kt) {
        #pragma unroll
        for (int i = 0; i < 4; ++i)
            GLOAD_LDS16(sb[i] + kt * 64, sm + buf * 16384 + dstL[i]);
    };

    f32x4 acc[4][4];
    #pragma unroll
    for (int mi = 0; mi < 4; ++mi)
        #pragma unroll
        for (int ni = 0; ni < 4; ++ni) acc[mi][ni] = (f32x4){0.f, 0.f, 0.f, 0.f};

    STAGE(0, 0);
    __syncthreads();
    int cur = 0;

    for (int kt = 0; kt < 16; ++kt) {
        bf16x8 av[2][4];
        if (actn) {
            #pragma unroll
            for (int ks = 0; ks < 2; ++ks)
                #pragma unroll
                for (int mi = 0; mi < 4; ++mi)
                    av[ks][mi] = *reinterpret_cast<const bf16x8*>(ap[mi] + kt * 64 + ks * 32);
        }
        if (kt < 15) STAGE(cur ^ 1, kt + 1);
        if (actn) {
            const char* bb = sm + cur * 16384;
            #pragma unroll
            for (int ks = 0; ks < 2; ++ks) {
                #pragma unroll
                for (int ni = 0; ni < 4; ++ni) {
                    int r = ni * 16 + lr;
                    const char* p = bb + r * 256 + (((ks * 128 + kg * 32)) ^ ((r & 7) << 5));
                    f32x4 lo = *reinterpret_cast<const f32x4*>(p);
                    f32x4 hi = *reinterpret_cast<const f32x4*>(p + 16);
                    bf16x8 bv;
                    #pragma unroll
                    for (int j = 0; j < 4; ++j) { bv[j] = f2bs(lo[j]); bv[4 + j] = f2bs(hi[j]); }
                    #pragma unroll
                    for (int mi = 0; mi < 4; ++mi)
                        if (mi < actn)
                            acc[mi][ni] = __builtin_amdgcn_mfma_f32_16x16x32_bf16(av[ks][mi], bv, acc[mi][ni], 0, 0, 0);
                }
            }
        }
        __syncthreads();
        cur ^= 1;
    }

    // epilogue: pair w1-frag (ni) with w3-frag (ni+2), silu multiply, store bf16
    #pragma unroll
    for (int mi = 0; mi < 4; ++mi) {
        if (mi >= actn) break;
        #pragma unroll
        for (int ni = 0; ni < 2; ++ni) {
            f32x4 d1 = acc[mi][ni], d3 = acc[mi][ni + 2];
            int fc = f0 + ni * 16 + lr;
            #pragma unroll
            for (int r = 0; r < 4; ++r) {
                int rl = wv * 64 + mi * 16 + kg * 4 + r;
                if (rl < nact) {
                    float v1 = d1[r];
                    float hv = (v1 / (1.f + expf(-v1))) * d3[r];
                    hbuf[(size_t)(offE + m0 + rl) * F_DIM + fc] = __float2bfloat16(hv);
                }
            }
        }
    }
}

// ---------------- ffn2: out += wgt * (h @ w2^T) ----------------
__global__ __launch_bounds__(256, 3) void ffn2_kernel(
    const float* __restrict__ w2,
    const __hip_bfloat16* __restrict__ hbuf,
    const int* __restrict__ cnt, const int* __restrict__ tok,
    const float* __restrict__ wgt,
    float* __restrict__ out)
{
    __shared__ char sm[32768];

    int e = blockIdx.y;
    int c[8];
    #pragma unroll
    for (int j = 0; j < 8; ++j) c[j] = cnt[j];
    int nt = c[e];
    int offE = 0;
    #pragma unroll
    for (int j = 0; j < 8; ++j) if (j < e) offE += c[j];

    int z = blockIdx.z;
    int ks4 = z & 3, mt = z >> 2;
    int m0 = mt * 256;
    if (m0 >= nt) return;
    int nact = min(nt - m0, 256);
    int n0 = blockIdx.x * 64;
    int kbeg = ks4 * 1024;

    int tid = threadIdx.x;
    int wv = tid >> 6, lane = tid & 63;
    int lr = lane & 15, kg = lane >> 4;
    int rem = nact - wv * 64;
    int actn = (rem <= 0) ? 0 : min((rem + 15) >> 4, 4);

    const float* w2e = w2 + (size_t)e * H_DIM * F_DIM;

    const __hip_bfloat16* ap[4];
    #pragma unroll
    for (int mi = 0; mi < 4; ++mi) {
        int rl = wv * 64 + mi * 16 + lr;
        int rc = min(rl, nact - 1);
        ap[mi] = hbuf + (size_t)(offE + m0 + rc) * F_DIM + kbeg + kg * 8;
    }

    const float* sb[4];
    int dstL[4];
    #pragma unroll
    for (int i = 0; i < 4; ++i) {
        int r = i * 16 + (tid >> 4);
        int cb = ((tid & 15) << 4) ^ ((r & 7) << 5);
        sb[i] = w2e + (size_t)(n0 + r) * F_DIM + kbeg + (cb >> 2);
        dstL[i] = i * 4096 + tid * 16;
    }

    auto STAGE = [&](int buf, int kt) {
        #pragma unroll
        for (int i = 0; i < 4; ++i)
            GLOAD_LDS16(sb[i] + kt * 64, sm + buf * 16384 + dstL[i]);
    };

    f32x4 acc[4][4];
    #pragma unroll
    for (int mi = 0; mi < 4; ++mi)
        #pragma unroll
        for (int ni = 0; ni < 4; ++ni) acc[mi][ni] = (f32x4){0.f, 0.f, 0.f, 0.f};

    STAGE(0, 0);
    __syncthreads();
    int cur = 0;

    for (int kt = 0; kt < 16; ++kt) {
        bf16x8 av[2][4];
        if (actn) {
            #pragma unroll
            for (int ks = 0; ks < 2; ++ks)
                #pragma unroll
                for (int mi = 0; mi < 4; ++mi)
                    av[ks][mi] = *reinterpret_cast<const bf16x8*>(ap[mi] + kt * 64 + ks * 32);
        }
        if (kt < 15) STAGE(cur ^ 1, kt + 1);
        if (actn) {
            const char* bb = sm + cur * 16384;
            #pragma unroll
            for (int ks = 0; ks < 2; ++ks) {
                #pragma unroll
                for (int ni = 0; ni < 4; ++ni) {
                    int r = ni * 16 + lr;
                    const char* p = bb + r * 256 + (((ks * 128 + kg * 32)) ^ ((r & 7) << 5));
                    f32x4 lo = *reinterpret_cast<const f32x4*>(p);
                    f32x4 hi = *reinterpret_cast<const f32x4*>(p + 16);
                    bf16x8 bv;
                    #pragma unroll
                    for (int j = 0; j < 4; ++j) { bv[j] = f2bs(lo[j]); bv[4 + j] = f2bs(hi[j]); }
                    #pragma unroll
                    for (int mi = 0; mi < 4; ++mi)
                        if (mi < actn)
                            acc[mi][ni] = __builtin_amdgcn_mfma_f32_16x16x32_bf16(av[ks][mi], bv, acc[mi][ni], 0, 0, 0);
                }
            }
        }
        __syncthreads();
        cur ^= 1;
    }

    #pragma unroll
    for (int mi = 0; mi < 4; ++mi) {
        if (mi >= actn) break;
        #pragma unroll
        for (int ni = 0; ni < 4; ++ni) {
            f32x4 d = acc[mi][ni];
            int col = n0 + ni * 16 + lr;
            #pragma unroll
            for (int r = 0; r < 4; ++r) {
                int rl = wv * 64 + mi * 16 + kg * 4 + r;
                if (rl < nact) {
                    int sl = m0 + rl;
                    int tt = tok[e * T_TOK + sl];
                    float wvv = wgt[e * T_TOK + sl];
                    atomicAdd(&out[(size_t)tt * H_DIM + col], wvv * d[r]);
                }
            }
        }
    }
}

extern "C" void kernel_launch(void* const* d_in, const int* in_sizes, int n_in,
                              void* d_out, int out_size, void* d_ws, size_t ws_size,
                              hipStream_t stream)
{
    const float* x  = (const float*)d_in[0];
    const float* gw = (const float*)d_in[1];
    const float* w1 = (const float*)d_in[2];
    const float* w2 = (const float*)d_in[3];
    const float* w3 = (const float*)d_in[4];
    float* out = (float*)d_out;

    char* ws = (char*)d_ws;
    int*   cnt = (int*)(ws);
    int*   tok = (int*)(ws + 256);
    float* wgt = (float*)(ws + 16640);
    __hip_bfloat16* xbf  = (__hip_bfloat16*)(ws + 33280);
    __hip_bfloat16* hbuf = (__hip_bfloat16*)(ws + 1081856);

    hipMemsetAsync(cnt, 0, 256, stream);
    hipMemsetAsync(out, 0, (size_t)out_size * sizeof(float), stream);

    routing_kernel<<<dim3(T_TOK / 4), 256, 0, stream>>>(x, gw, cnt, tok, wgt, xbf);
    ffn1_kernel<<<dim3(F_DIM / 32, NEXP, 2), 256, 0, stream>>>(w1, w3, xbf, hbuf, cnt, tok);
    ffn2_kernel<<<dim3(H_DIM / 64, NEXP, 8), 256, 0, stream>>>(w2, hbuf, cnt, tok, wgt, out);
}